// Round 1
// baseline (2174.922 us; speedup 1.0000x reference)
//
#include <hip/hip_runtime.h>
#include <hip/hip_bf16.h>

// GCN forward: h1 = relu(Agg(x@W1) + b1); h2 = relu(Agg(h1@W2) + b2);
// out = meanpool_by_graph(h2) @ fcW + fcb
// Agg(h)[v] = sum_{e: dst=v} h[src_e]*dnorm[src]*dnorm[dst] + h[v]*dnorm[v]^2
// dnorm[v] = 1/sqrt(indeg(v)+1)

#define F_IN 256
#define HDIM 64

__global__ __launch_bounds__(256) void deg_count_kernel(
    const int* __restrict__ dst, float* __restrict__ deg, int E) {
  int t = blockIdx.x * 256 + threadIdx.x;
  if (t < E) atomicAdd(&deg[dst[t]], 1.0f);
}

__global__ __launch_bounds__(256) void deg_fin_kernel(float* __restrict__ deg, int N) {
  int t = blockIdx.x * 256 + threadIdx.x;
  if (t < N) deg[t] = 1.0f / sqrtf(deg[t] + 1.0f);
}

// out[N,64] = X[N,K] @ W[K,64].  Block = 256 thr = 4 waves; each wave does 8 rows,
// lane = output column. W staged in LDS; x row elements fetched via wave-uniform
// scalar loads (readfirstlane forces wave id into SGPR).
template <int K>
__global__ __launch_bounds__(256) void gemm_kernel(
    const float* __restrict__ X, const float* __restrict__ W,
    float* __restrict__ out, int N) {
  __shared__ float w[K * 64];
  for (int i = threadIdx.x; i < K * 64; i += 256) w[i] = W[i];
  __syncthreads();
  const int lane = threadIdx.x & 63;
  const int wave = __builtin_amdgcn_readfirstlane((int)(threadIdx.x >> 6));
  long base = ((long)blockIdx.x * 4 + wave) * 8;
  if (base >= N) return;
  const float* xr = X + base * K;
  float acc[8];
#pragma unroll
  for (int r = 0; r < 8; ++r) acc[r] = 0.f;
  if (base + 8 <= N) {
#pragma unroll 4
    for (int k = 0; k < K; ++k) {
      float wv = w[k * 64 + lane];
#pragma unroll
      for (int r = 0; r < 8; ++r)
        acc[r] = fmaf(xr[(size_t)r * K + k], wv, acc[r]);
    }
#pragma unroll
    for (int r = 0; r < 8; ++r) out[(base + r) * 64 + lane] = acc[r];
  } else {
    int rows = (int)(N - base);
    for (int k = 0; k < K; ++k) {
      float wv = w[k * 64 + lane];
      for (int r = 0; r < rows; ++r)
        acc[r] = fmaf(xr[(size_t)r * K + k], wv, acc[r]);
    }
    for (int r = 0; r < rows; ++r) out[(base + r) * 64 + lane] = acc[r];
  }
}

// One wave per edge (16 edges per wave via loop), lane = channel.
// src/dst/norm are wave-uniform -> scalar loads; gather + atomic are coalesced.
__global__ __launch_bounds__(256) void aggregate_kernel(
    const float* __restrict__ h, const int* __restrict__ src,
    const int* __restrict__ dst, const float* __restrict__ dnorm,
    float* __restrict__ agg, int E) {
  const int lane = threadIdx.x & 63;
  const int wave = __builtin_amdgcn_readfirstlane((int)(threadIdx.x >> 6));
  long e0 = ((long)blockIdx.x * 4 + wave) * 16;
  for (int i = 0; i < 16; ++i) {
    long e = e0 + i;
    if (e < E) {
      int s = src[e];
      int d = dst[e];
      float nrm = dnorm[s] * dnorm[d];
      float val = h[(size_t)s * 64 + lane] * nrm;
      atomicAdd(&agg[(size_t)d * 64 + lane], val);
    }
  }
}

// h_out = relu(agg + hlin*dnorm^2 (self loop) + bias)
__global__ __launch_bounds__(256) void finalize_kernel(
    const float* __restrict__ agg, const float* __restrict__ hlin,
    const float* __restrict__ dnorm, const float* __restrict__ bias,
    float* __restrict__ hout, long total) {
  long i = (long)blockIdx.x * 256 + threadIdx.x;
  if (i < total) {
    long v = i >> 6;
    int c = (int)(i & 63);
    float dq = dnorm[v];
    float val = agg[i] + hlin[i] * dq * dq + bias[c];
    hout[i] = fmaxf(val, 0.f);
  }
}

// Fused layer-2 epilogue + pooling: relu(agg + hlin*dq^2 + b2) scattered into
// per-graph sums. One wave per node (16 nodes/wave), lane = channel.
__global__ __launch_bounds__(256) void pool_fin_kernel(
    const float* __restrict__ agg, const float* __restrict__ hlin,
    const float* __restrict__ dnorm, const float* __restrict__ bias,
    const int* __restrict__ batch, float* __restrict__ pooled,
    float* __restrict__ cnt, int N) {
  const int lane = threadIdx.x & 63;
  const int wave = __builtin_amdgcn_readfirstlane((int)(threadIdx.x >> 6));
  long v0 = ((long)blockIdx.x * 4 + wave) * 16;
  for (int i = 0; i < 16; ++i) {
    long v = v0 + i;
    if (v < N) {
      float dq = dnorm[v];
      float val = agg[v * 64 + lane] + hlin[v * 64 + lane] * dq * dq + bias[lane];
      val = fmaxf(val, 0.f);
      int g = batch[v];
      atomicAdd(&pooled[(size_t)g * 64 + lane], val);
      if (lane == 0) atomicAdd(&cnt[g], 1.0f);
    }
  }
}

__global__ __launch_bounds__(256) void final_fc_kernel(
    const float* __restrict__ pooled, const float* __restrict__ cnt,
    const float* __restrict__ fcW, const float* __restrict__ fcb,
    float* __restrict__ out, int G) {
  int t = blockIdx.x * 256 + threadIdx.x;
  if (t < G * 2) {
    int g = t >> 1, c = t & 1;
    float inv = 1.0f / fmaxf(cnt[g], 1.0f);
    float acc = fcb[c];
#pragma unroll
    for (int h = 0; h < 64; ++h)
      acc = fmaf(pooled[g * 64 + h] * inv, fcW[h * 2 + c], acc);
    out[t] = acc;
  }
}

extern "C" void kernel_launch(void* const* d_in, const int* in_sizes, int n_in,
                              void* d_out, int out_size, void* d_ws, size_t ws_size,
                              hipStream_t stream) {
  const float* x   = (const float*)d_in[0];
  const int*   ei  = (const int*)d_in[1];
  const int*   bat = (const int*)d_in[2];
  const float* W1  = (const float*)d_in[3];
  const float* b1  = (const float*)d_in[4];
  const float* W2  = (const float*)d_in[5];
  const float* b2  = (const float*)d_in[6];
  const float* fcW = (const float*)d_in[7];
  const float* fcb = (const float*)d_in[8];
  float* out = (float*)d_out;

  const int N = in_sizes[0] / F_IN;      // 100000
  const int E = in_sizes[1] / 2;         // 3200000
  const int G = out_size / 2;            // 128
  const int* src = ei;
  const int* dst = ei + E;

  float* ws = (float*)d_ws;
  float* dnorm  = ws;                          // N
  float* A      = ws + 102400;                 // hlin (N*64)
  float* B      = A + (size_t)N * 64;          // agg  (N*64)
  float* Cb     = B + (size_t)N * 64;          // h1   (N*64)
  float* pooled = Cb + (size_t)N * 64;         // G*64
  float* cnt    = pooled + (size_t)G * 64;     // G

  // degree -> dnorm
  hipMemsetAsync(dnorm, 0, (size_t)N * sizeof(float), stream);
  deg_count_kernel<<<(E + 255) / 256, 256, 0, stream>>>(dst, dnorm, E);
  deg_fin_kernel<<<(N + 255) / 256, 256, 0, stream>>>(dnorm, N);

  // layer 1
  gemm_kernel<F_IN><<<(N + 31) / 32, 256, 0, stream>>>(x, W1, A, N);
  hipMemsetAsync(B, 0, (size_t)N * 64 * sizeof(float), stream);
  aggregate_kernel<<<(E + 63) / 64, 256, 0, stream>>>(A, src, dst, dnorm, B, E);
  finalize_kernel<<<((long)N * 64 + 255) / 256, 256, 0, stream>>>(B, A, dnorm, b1, Cb, (long)N * 64);

  // layer 2
  gemm_kernel<HDIM><<<(N + 31) / 32, 256, 0, stream>>>(Cb, W2, A, N);
  hipMemsetAsync(B, 0, (size_t)N * 64 * sizeof(float), stream);
  aggregate_kernel<<<(E + 63) / 64, 256, 0, stream>>>(A, src, dst, dnorm, B, E);

  // pooling (fused layer-2 epilogue) + FC
  hipMemsetAsync(pooled, 0, (size_t)(G * 64 + G) * sizeof(float), stream);
  pool_fin_kernel<<<(N + 63) / 64, 256, 0, stream>>>(B, A, dnorm, b2, bat, pooled, cnt, N);
  final_fc_kernel<<<1, 256, 0, stream>>>(pooled, cnt, fcW, fcb, out, G);
}

// Round 2
// 1144.173 us; speedup vs baseline: 1.9009x; 1.9009x over previous
//
#include <hip/hip_runtime.h>
#include <hip/hip_bf16.h>

// GCN forward, CSR gather-side formulation:
//   hs = (X@W) * dnorm[v]          (GEMM epilogue scaling)
//   h_out[v] = relu(dnorm[v] * (hs[v] + sum_{e:dst=v} hs[src_e]) + b)
// CSR (counting sort by dst) built once per launch, reused by both layers.

#define F_IN 256
#define HDIM 64

// ---------------- CSR build ----------------

__global__ __launch_bounds__(256) void deg_count_kernel(
    const int* __restrict__ dst, int* __restrict__ counts, int E) {
  int t = blockIdx.x * 256 + threadIdx.x;
  if (t < E) atomicAdd(&counts[dst[t]], 1);
}

// per-block (1024-element chunk) sums
__global__ __launch_bounds__(256) void block_sum_kernel(
    const int* __restrict__ counts, int* __restrict__ bs, int N) {
  __shared__ int s[256];
  int b = blockIdx.x, tid = threadIdx.x;
  int base = b * 1024 + tid * 4;
  int sum = 0;
#pragma unroll
  for (int i = 0; i < 4; ++i) if (base + i < N) sum += counts[base + i];
  s[tid] = sum;
  __syncthreads();
  for (int off = 128; off > 0; off >>= 1) {
    if (tid < off) s[tid] += s[tid + off];
    __syncthreads();
  }
  if (tid == 0) bs[b] = s[0];
}

// exclusive scan of block sums (nb <= 256), rowptr[N] = E
__global__ __launch_bounds__(256) void scan_blocksums_kernel(
    int* __restrict__ bs, int nb, int* __restrict__ rowptr, int N, int E) {
  __shared__ int s[256];
  int tid = threadIdx.x;
  int x = (tid < nb) ? bs[tid] : 0;
  s[tid] = x;
  __syncthreads();
  for (int off = 1; off < 256; off <<= 1) {
    int t = (tid >= off) ? s[tid - off] : 0;
    __syncthreads();
    s[tid] += t;
    __syncthreads();
  }
  if (tid < nb) bs[tid] = s[tid] - x;  // exclusive
  if (tid == 0) rowptr[N] = E;
}

// final scan: rowptr, cursor copy, dnorm = rsqrt(deg+1)
__global__ __launch_bounds__(256) void scan_final_kernel(
    const int* __restrict__ counts, const int* __restrict__ bs,
    int* __restrict__ rowptr, int* __restrict__ cursor,
    float* __restrict__ dnorm, int N) {
  __shared__ int s[256];
  int b = blockIdx.x, tid = threadIdx.x;
  int base = b * 1024 + tid * 4;
  int c[4];
  int sum = 0;
#pragma unroll
  for (int i = 0; i < 4; ++i) {
    c[i] = (base + i < N) ? counts[base + i] : 0;
    sum += c[i];
  }
  int x = sum;
  s[tid] = x;
  __syncthreads();
  for (int off = 1; off < 256; off <<= 1) {
    int t = (tid >= off) ? s[tid - off] : 0;
    __syncthreads();
    s[tid] += t;
    __syncthreads();
  }
  int off0 = bs[b] + s[tid] - x;
#pragma unroll
  for (int i = 0; i < 4; ++i) {
    if (base + i < N) {
      rowptr[base + i] = off0;
      cursor[base + i] = off0;
      dnorm[base + i] = rsqrtf((float)c[i] + 1.0f);
      off0 += c[i];
    }
  }
}

__global__ __launch_bounds__(256) void scatter_kernel(
    const int* __restrict__ src, const int* __restrict__ dst,
    int* __restrict__ cursor, int* __restrict__ csr, int E) {
  int t = blockIdx.x * 256 + threadIdx.x;
  if (t < E) {
    int d = dst[t];
    int pos = atomicAdd(&cursor[d], 1);
    csr[pos] = src[t];
  }
}

// ---------------- GEMM (out scaled by dnorm) ----------------
// out[N,64] = (X[N,K] @ W[K,64]) * dnorm[row]. Wave = 8 rows, lane = col.
template <int K>
__global__ __launch_bounds__(256) void gemm_kernel(
    const float* __restrict__ X, const float* __restrict__ W,
    const float* __restrict__ dnorm, float* __restrict__ out, int N) {
  __shared__ float w[K * 64];
  for (int i = threadIdx.x; i < K * 64; i += 256) w[i] = W[i];
  __syncthreads();
  const int lane = threadIdx.x & 63;
  const int wave = __builtin_amdgcn_readfirstlane((int)(threadIdx.x >> 6));
  long base = ((long)blockIdx.x * 4 + wave) * 8;
  if (base >= N) return;
  const float* xr = X + base * K;
  float acc[8];
#pragma unroll
  for (int r = 0; r < 8; ++r) acc[r] = 0.f;
  if (base + 8 <= N) {
#pragma unroll 4
    for (int k = 0; k < K; ++k) {
      float wv = w[k * 64 + lane];
#pragma unroll
      for (int r = 0; r < 8; ++r)
        acc[r] = fmaf(xr[(size_t)r * K + k], wv, acc[r]);
    }
#pragma unroll
    for (int r = 0; r < 8; ++r)
      out[(base + r) * 64 + lane] = acc[r] * dnorm[base + r];
  } else {
    int rows = (int)(N - base);
    for (int k = 0; k < K; ++k) {
      float wv = w[k * 64 + lane];
      for (int r = 0; r < rows; ++r)
        acc[r] = fmaf(xr[(size_t)r * K + k], wv, acc[r]);
    }
    for (int r = 0; r < rows; ++r)
      out[(base + r) * 64 + lane] = acc[r] * dnorm[base + r];
  }
}

// ---------------- Gather aggregation ----------------
// One wave per node, lane = channel. hout = relu(dnorm[v]*(hs[v]+sum) + b)
__global__ __launch_bounds__(256) void gather_agg_kernel(
    const float* __restrict__ hs, const int* __restrict__ rowptr,
    const int* __restrict__ csr, const float* __restrict__ dnorm,
    const float* __restrict__ bias, float* __restrict__ hout, int N) {
  const int lane = threadIdx.x & 63;
  const int wave = __builtin_amdgcn_readfirstlane((int)(threadIdx.x >> 6));
  int v = blockIdx.x * 4 + wave;
  if (v >= N) return;
  int beg = rowptr[v], end = rowptr[v + 1];
  float a0 = hs[(size_t)v * 64 + lane], a1 = 0.f, a2 = 0.f, a3 = 0.f;
  int j = beg;
  for (; j + 4 <= end; j += 4) {
    int s0 = csr[j], s1 = csr[j + 1], s2 = csr[j + 2], s3 = csr[j + 3];
    a0 += hs[(size_t)s0 * 64 + lane];
    a1 += hs[(size_t)s1 * 64 + lane];
    a2 += hs[(size_t)s2 * 64 + lane];
    a3 += hs[(size_t)s3 * 64 + lane];
  }
  for (; j < end; ++j) a0 += hs[(size_t)csr[j] * 64 + lane];
  float val = dnorm[v] * ((a0 + a1) + (a2 + a3)) + bias[lane];
  hout[(size_t)v * 64 + lane] = fmaxf(val, 0.f);
}

// Layer-2 variant: fused with mean-pool scatter (atomic into [G,64] sums)
__global__ __launch_bounds__(256) void gather_agg_pool_kernel(
    const float* __restrict__ hs, const int* __restrict__ rowptr,
    const int* __restrict__ csr, const float* __restrict__ dnorm,
    const float* __restrict__ bias, const int* __restrict__ batch,
    float* __restrict__ pooled, int N) {
  const int lane = threadIdx.x & 63;
  const int wave = __builtin_amdgcn_readfirstlane((int)(threadIdx.x >> 6));
  int v = blockIdx.x * 4 + wave;
  if (v >= N) return;
  int beg = rowptr[v], end = rowptr[v + 1];
  float a0 = hs[(size_t)v * 64 + lane], a1 = 0.f, a2 = 0.f, a3 = 0.f;
  int j = beg;
  for (; j + 4 <= end; j += 4) {
    int s0 = csr[j], s1 = csr[j + 1], s2 = csr[j + 2], s3 = csr[j + 3];
    a0 += hs[(size_t)s0 * 64 + lane];
    a1 += hs[(size_t)s1 * 64 + lane];
    a2 += hs[(size_t)s2 * 64 + lane];
    a3 += hs[(size_t)s3 * 64 + lane];
  }
  for (; j < end; ++j) a0 += hs[(size_t)csr[j] * 64 + lane];
  float val = dnorm[v] * ((a0 + a1) + (a2 + a3)) + bias[lane];
  val = fmaxf(val, 0.f);
  int g = batch[v];
  atomicAdd(&pooled[(size_t)g * 64 + lane], val);
}

// ---------------- Final FC (counts via binary search on sorted batch) -------
__global__ __launch_bounds__(256) void final_fc_kernel(
    const float* __restrict__ pooled, const int* __restrict__ batch,
    const float* __restrict__ fcW, const float* __restrict__ fcb,
    float* __restrict__ out, int G, int N) {
  int t = blockIdx.x * 256 + threadIdx.x;
  if (t < G * 2) {
    int g = t >> 1, c = t & 1;
    int lo = 0, hi = N;
    while (lo < hi) { int m = (lo + hi) >> 1; if (batch[m] < g) lo = m + 1; else hi = m; }
    int lb = lo;
    lo = 0; hi = N;
    while (lo < hi) { int m = (lo + hi) >> 1; if (batch[m] <= g) lo = m + 1; else hi = m; }
    int cntg = lo - lb;
    float inv = 1.0f / fmaxf((float)cntg, 1.0f);
    float acc = fcb[c];
#pragma unroll
    for (int h = 0; h < 64; ++h)
      acc = fmaf(pooled[g * 64 + h] * inv, fcW[h * 2 + c], acc);
    out[t] = acc;
  }
}

extern "C" void kernel_launch(void* const* d_in, const int* in_sizes, int n_in,
                              void* d_out, int out_size, void* d_ws, size_t ws_size,
                              hipStream_t stream) {
  const float* x   = (const float*)d_in[0];
  const int*   ei  = (const int*)d_in[1];
  const int*   bat = (const int*)d_in[2];
  const float* W1  = (const float*)d_in[3];
  const float* b1  = (const float*)d_in[4];
  const float* W2  = (const float*)d_in[5];
  const float* b2  = (const float*)d_in[6];
  const float* fcW = (const float*)d_in[7];
  const float* fcb = (const float*)d_in[8];
  float* out = (float*)d_out;

  const int N = in_sizes[0] / F_IN;      // 100000
  const int E = in_sizes[1] / 2;         // 3200000
  const int G = out_size / 2;            // 128
  const int* src = ei;
  const int* dst = ei + E;

  const int nb = (N + 1023) / 1024;      // scan chunks (98)

  char* w = (char*)d_ws;
  int*   counts  = (int*)w;                       w += (size_t)N * 4;
  int*   rowptr  = (int*)w;                       w += (size_t)(N + 1) * 4;
  int*   cursor  = (int*)w;                       w += (size_t)N * 4;
  int*   bs      = (int*)w;                       w += 1024;
  float* dnorm   = (float*)w;                     w += (size_t)N * 4;
  int*   csr     = (int*)w;                       w += (size_t)E * 4;
  float* hs      = (float*)w;                     w += (size_t)N * 64 * 4;
  float* h1      = (float*)w;                     w += (size_t)N * 64 * 4;
  float* pooled  = (float*)w;                     w += (size_t)G * 64 * 4;

  // --- CSR build + dnorm ---
  hipMemsetAsync(counts, 0, (size_t)N * 4, stream);
  hipMemsetAsync(pooled, 0, (size_t)G * 64 * 4, stream);
  deg_count_kernel<<<(E + 255) / 256, 256, 0, stream>>>(dst, counts, E);
  block_sum_kernel<<<nb, 256, 0, stream>>>(counts, bs, N);
  scan_blocksums_kernel<<<1, 256, 0, stream>>>(bs, nb, rowptr, N, E);
  scan_final_kernel<<<nb, 256, 0, stream>>>(counts, bs, rowptr, cursor, dnorm, N);
  scatter_kernel<<<(E + 255) / 256, 256, 0, stream>>>(src, dst, cursor, csr, E);

  // --- layer 1 ---
  gemm_kernel<F_IN><<<(N + 31) / 32, 256, 0, stream>>>(x, W1, dnorm, hs, N);
  gather_agg_kernel<<<(N + 3) / 4, 256, 0, stream>>>(hs, rowptr, csr, dnorm, b1, h1, N);

  // --- layer 2 (epilogue fused with pooling) ---
  gemm_kernel<HDIM><<<(N + 31) / 32, 256, 0, stream>>>(h1, W2, dnorm, hs, N);
  gather_agg_pool_kernel<<<(N + 3) / 4, 256, 0, stream>>>(hs, rowptr, csr, dnorm, b2, bat, pooled, N);

  // --- FC ---
  final_fc_kernel<<<1, 256, 0, stream>>>(pooled, bat, fcW, fcb, out, G, N);
}